// Round 1
// baseline (341.944 us; speedup 1.0000x reference)
//
#include <hip/hip_runtime.h>
#include <hip/hip_bf16.h>

// PLRNN step: out = A*z + relu(z - rowmean(z)) @ W^T + h,  A=diag(AW), W=AW-diag
// Rewritten as: out = (z_act @ AW^T) + A*min(z, mu) + h   (exact identity)
// B=65536, DZ=512. bf16 MFMA GEMM (fp32 accum), fp32 epilogue correction.

#define DZV 512
#define BM 64
#define LDA 520   // LDS row stride in bf16 elems: 1040B, 16B-aligned, breaks pow2 bank aliasing

typedef __attribute__((ext_vector_type(8))) short short8;  // 8 bf16 = 4 VGPRs (MFMA A/B frag)
typedef __attribute__((ext_vector_type(4))) float f32x4;   // MFMA C/D frag

__device__ __forceinline__ unsigned short f2bf(float x) {
  __hip_bfloat16 b = __float2bfloat16(x);
  return __builtin_bit_cast(unsigned short, b);
}

// Kernel 0: AW fp32 -> bf16 into workspace (runs every call; ws is re-poisoned each call)
__global__ void cvt_aw(const float* __restrict__ AW, unsigned short* __restrict__ AWb) {
  int i = blockIdx.x * 256 + threadIdx.x;          // 65536 threads x 4 elems = 512*512
  float4 v = ((const float4*)AW)[i];
  ushort4 p;
  p.x = f2bf(v.x); p.y = f2bf(v.y); p.z = f2bf(v.z); p.w = f2bf(v.w);
  ((ushort4*)AWb)[i] = p;
}

__global__ __launch_bounds__(512, 4) void plrnn_step(
    const float* __restrict__ z, const float* __restrict__ AW,
    const float* __restrict__ h, const unsigned short* __restrict__ AWb,
    float* __restrict__ out)
{
  __shared__ unsigned short sA[BM * LDA];  // z_act panel, bf16, 66560 B
  __shared__ float sMu[BM];

  const int t = threadIdx.x;
  const int row0 = blockIdx.x * BM;

  // ---- Phase 1: load z panel, row means, relu, bf16 -> LDS (single pass over z) ----
  {
    const int r  = t >> 3;   // 0..63  (8 threads per row)
    const int c8 = t & 7;
    const float4* zr = (const float4*)(z + (row0 + r) * DZV);
    float4 v[16];
    float s = 0.f;
    #pragma unroll
    for (int i = 0; i < 16; ++i) {
      v[i] = zr[c8 + i * 8];                      // coalesced: 8 rows x 128B per instr
      s += (v[i].x + v[i].y) + (v[i].z + v[i].w);
    }
    s += __shfl_xor(s, 1);                        // 8 row-threads are consecutive lanes
    s += __shfl_xor(s, 2);
    s += __shfl_xor(s, 4);
    const float mu = s * (1.0f / 512.0f);
    if (c8 == 0) sMu[r] = mu;
    #pragma unroll
    for (int i = 0; i < 16; ++i) {
      ushort4 p;
      p.x = f2bf(fmaxf(v[i].x - mu, 0.f));
      p.y = f2bf(fmaxf(v[i].y - mu, 0.f));
      p.z = f2bf(fmaxf(v[i].z - mu, 0.f));
      p.w = f2bf(fmaxf(v[i].w - mu, 0.f));
      *(ushort4*)&sA[r * LDA + (c8 + i * 8) * 4] = p;
    }
  }
  __syncthreads();   // the ONLY barrier: K-loop below is barrier-free

  // ---- Phase 2: GEMM. Each wave: 4 M-tiles x 4 N-tiles (16x16x32 MFMA) ----
  const int lane  = t & 63;
  const int wave  = t >> 6;        // 8 waves cover N=512 in 64-col slices
  const int lr    = lane & 15;
  const int quad  = lane >> 4;
  const int nbase = wave * 64;

  f32x4 acc[4][4];
  #pragma unroll
  for (int mt = 0; mt < 4; ++mt)
    #pragma unroll
    for (int nt = 0; nt < 4; ++nt)
      acc[mt][nt] = (f32x4){0.f, 0.f, 0.f, 0.f};

  // B frags straight from L2 (AWb is hot & shared by all blocks): B[n=lr][k=quad*8+j]
  const unsigned short* bbase[4];
  #pragma unroll
  for (int nt = 0; nt < 4; ++nt)
    bbase[nt] = AWb + (nbase + nt * 16 + lr) * DZV + quad * 8;
  // A frags from LDS: A[m=lr][k=quad*8+j]
  const unsigned short* abase[4];
  #pragma unroll
  for (int mt = 0; mt < 4; ++mt)
    abase[mt] = &sA[(mt * 16 + lr) * LDA + quad * 8];

  #pragma unroll 2
  for (int k = 0; k < DZV; k += 32) {
    short8 bf[4], af[4];
    #pragma unroll
    for (int nt = 0; nt < 4; ++nt)
      bf[nt] = *(const short8*)(bbase[nt] + k);   // global_load_dwordx4 from L2
    #pragma unroll
    for (int mt = 0; mt < 4; ++mt)
      af[mt] = *(const short8*)(abase[mt] + k);   // ds_read_b128
    #pragma unroll
    for (int mt = 0; mt < 4; ++mt)
      #pragma unroll
      for (int nt = 0; nt < 4; ++nt)
        acc[mt][nt] = __builtin_amdgcn_mfma_f32_16x16x32_bf16(af[mt], bf[nt], acc[mt][nt], 0, 0, 0);
  }

  // ---- Epilogue: out = acc + A[j]*min(z, mu) + h[j]  (exact fp32 correction) ----
  #pragma unroll
  for (int nt = 0; nt < 4; ++nt) {
    const int gn  = nbase + nt * 16 + lr;
    const float Ad = AW[gn * (DZV + 1)];   // diagonal, fp32, L2-hot
    const float hv = h[gn];
    #pragma unroll
    for (int mt = 0; mt < 4; ++mt) {
      #pragma unroll
      for (int r = 0; r < 4; ++r) {
        const int lm = mt * 16 + quad * 4 + r;    // C/D layout: row = quad*4 + reg
        const int gm = row0 + lm;
        const float mu = sMu[lm];
        const float zv = z[gm * DZV + gn];        // re-read z (L2/L3-warm from phase 1)
        const float res = acc[mt][nt][r] + Ad * fminf(zv, mu) + hv;
        __builtin_nontemporal_store(res, &out[gm * DZV + gn]);  // streaming store
      }
    }
  }
}

extern "C" void kernel_launch(void* const* d_in, const int* in_sizes, int n_in,
                              void* d_out, int out_size, void* d_ws, size_t ws_size,
                              hipStream_t stream) {
  const float* z  = (const float*)d_in[0];
  const float* AW = (const float*)d_in[1];
  const float* h  = (const float*)d_in[2];
  float* out = (float*)d_out;
  unsigned short* AWb = (unsigned short*)d_ws;   // 512KB bf16 copy of AW

  cvt_aw<<<256, 256, 0, stream>>>(AW, AWb);
  plrnn_step<<<65536 / BM, 512, 0, stream>>>(z, AW, h, AWb, out);
}

// Round 2
// 279.046 us; speedup vs baseline: 1.2254x; 1.2254x over previous
//
#include <hip/hip_runtime.h>
#include <hip/hip_bf16.h>

// PLRNN step: out = A*z + relu(z - rowmean(z)) @ W^T + h,  A=diag(AW), W=AW-diag
// Rewritten: out = (z_act @ AW^T) + [A*min(z,mu) + h]   (exact identity)
// Round 2: B packed in MFMA-frag order (coalesced L2 loads), correction term
// computed in phase 1 (coalesced) into a bf16 LDS panel -> no scattered z re-read,
// plain stores (L2 line merging). BM=32, two 33KB LDS panels, 2 blocks/CU.

#define DZV 512
#define BM 32
#define LDA 520   // LDS row stride (shorts): 1040 B = 65*16 -> 16B aligned, non-pow2 banks

typedef __attribute__((ext_vector_type(8))) short short8;  // 8 bf16 = 4 VGPRs
typedef __attribute__((ext_vector_type(4))) float f32x4;   // MFMA C/D frag

__device__ __forceinline__ unsigned short f2bf(float x) {
  __hip_bfloat16 b = __float2bfloat16(x);
  return __builtin_bit_cast(unsigned short, b);
}
__device__ __forceinline__ float bf2f(unsigned short u) {
  return __builtin_bit_cast(float, (unsigned int)u << 16);
}

// Prep: pack AW (fp32) into bf16 MFMA-B-fragment order + extract diagonal.
// Packed layout: frag index idx=(T*16+s)*64+L holds 8 bf16 = AW[T*16+(L&15)][s*32+(L>>4)*8 + j]
// so a wave's B-frag load (lane L reads idx base + L) is 1KB contiguous.
__global__ void pack_b(const float* __restrict__ AW, unsigned short* __restrict__ AWp,
                       float* __restrict__ Adiag) {
  int idx = blockIdx.x * 256 + threadIdx.x;     // 0..32767
  int L = idx & 63, s = (idx >> 6) & 15, T = idx >> 10;
  int n = T * 16 + (L & 15);
  int k = s * 32 + (L >> 4) * 8;
  const float4* src = (const float4*)(AW + n * DZV + k);
  float4 a = src[0], b = src[1];
  union { unsigned short u[8]; short8 v; } p;
  p.u[0] = f2bf(a.x); p.u[1] = f2bf(a.y); p.u[2] = f2bf(a.z); p.u[3] = f2bf(a.w);
  p.u[4] = f2bf(b.x); p.u[5] = f2bf(b.y); p.u[6] = f2bf(b.z); p.u[7] = f2bf(b.w);
  *(short8*)(AWp + idx * 8) = p.v;
  if (idx < DZV) Adiag[idx] = AW[idx * (DZV + 1)];
}

__global__ __launch_bounds__(512, 4) void plrnn_step(
    const float* __restrict__ z, const float* __restrict__ h,
    const unsigned short* __restrict__ AWp, const float* __restrict__ Adiag,
    float* __restrict__ out)
{
  __shared__ unsigned short sA[BM * LDA];  // z_act panel (bf16), 33.3 KB
  __shared__ unsigned short sC[BM * LDA];  // corr = A*min(z,mu)+h panel (bf16), 33.3 KB

  const int t = threadIdx.x;
  const int row0 = blockIdx.x * BM;

  // ---- Phase 1: single coalesced pass over z; mean, relu->sA, corr->sC ----
  {
    const int r = t >> 4;          // 0..31, 16 threads per row (consecutive lanes)
    const int c = t & 15;
    const float4* zr = (const float4*)(z + (row0 + r) * DZV);
    float4 v[8];
    float s = 0.f;
    #pragma unroll
    for (int i = 0; i < 8; ++i) {
      v[i] = zr[c + i * 16];                   // coalesced: 16 lanes x 16B = 256B runs
      s += (v[i].x + v[i].y) + (v[i].z + v[i].w);
    }
    s += __shfl_xor(s, 1);
    s += __shfl_xor(s, 2);
    s += __shfl_xor(s, 4);
    s += __shfl_xor(s, 8);
    const float mu = s * (1.0f / 512.0f);
    #pragma unroll
    for (int i = 0; i < 8; ++i) {
      const int c4 = c + i * 16;               // float4 column index
      float4 Ad = ((const float4*)Adiag)[c4];  // L1/L2-hot, 2KB shared
      float4 hv = ((const float4*)h)[c4];
      union { unsigned short u[4]; ushort2 h2[2]; } pa, pc;
      pa.u[0] = f2bf(fmaxf(v[i].x - mu, 0.f));
      pa.u[1] = f2bf(fmaxf(v[i].y - mu, 0.f));
      pa.u[2] = f2bf(fmaxf(v[i].z - mu, 0.f));
      pa.u[3] = f2bf(fmaxf(v[i].w - mu, 0.f));
      pc.u[0] = f2bf(Ad.x * fminf(v[i].x, mu) + hv.x);
      pc.u[1] = f2bf(Ad.y * fminf(v[i].y, mu) + hv.y);
      pc.u[2] = f2bf(Ad.z * fminf(v[i].z, mu) + hv.z);
      pc.u[3] = f2bf(Ad.w * fminf(v[i].w, mu) + hv.w);
      *(ushort4*)&sA[r * LDA + c4 * 4] = *(ushort4*)pa.u;
      *(ushort4*)&sC[r * LDA + c4 * 4] = *(ushort4*)pc.u;
    }
  }
  __syncthreads();   // only barrier; K-loop below is barrier-free

  // ---- Phase 2: GEMM. Wave: 2 M-tiles x 4 N-tiles, 16x16x32 bf16 MFMA ----
  const int lane = t & 63;
  const int wave = t >> 6;           // 8 waves cover N=512
  const int lr   = lane & 15;
  const int quad = lane >> 4;
  const int nbase = wave * 64;

  f32x4 acc[2][4];
  #pragma unroll
  for (int mt = 0; mt < 2; ++mt)
    #pragma unroll
    for (int nt = 0; nt < 4; ++nt)
      acc[mt][nt] = (f32x4){0.f, 0.f, 0.f, 0.f};

  // A frags from LDS: A[m=lr][k=quad*8+j]
  const unsigned short* a0 = &sA[(lr) * LDA + quad * 8];
  const unsigned short* a1 = &sA[(16 + lr) * LDA + quad * 8];
  // B frags from packed global (L2-hot, lane-contiguous 1KB/instr)
  const unsigned short* bb[4];
  #pragma unroll
  for (int nt = 0; nt < 4; ++nt)
    bb[nt] = AWp + (((wave * 4 + nt) * 16) * 64 + lane) * 8;

  #pragma unroll 4
  for (int s = 0; s < 16; ++s) {     // k = s*32
    short8 bf[4], af[2];
    #pragma unroll
    for (int nt = 0; nt < 4; ++nt)
      bf[nt] = *(const short8*)(bb[nt] + s * 512);   // global_load_dwordx4, coalesced
    af[0] = *(const short8*)(a0 + s * 32);           // ds_read_b128
    af[1] = *(const short8*)(a1 + s * 32);
    #pragma unroll
    for (int nt = 0; nt < 4; ++nt) {
      acc[0][nt] = __builtin_amdgcn_mfma_f32_16x16x32_bf16(af[0], bf[nt], acc[0][nt], 0, 0, 0);
      acc[1][nt] = __builtin_amdgcn_mfma_f32_16x16x32_bf16(af[1], bf[nt], acc[1][nt], 0, 0, 0);
    }
  }

  // ---- Epilogue: out = acc + corr (corr already has A*min(z,mu)+h) ----
  #pragma unroll
  for (int nt = 0; nt < 4; ++nt) {
    const int gn = nbase + nt * 16 + lr;
    #pragma unroll
    for (int mt = 0; mt < 2; ++mt) {
      #pragma unroll
      for (int r = 0; r < 4; ++r) {
        const int lm = mt * 16 + quad * 4 + r;   // C/D layout: row = quad*4 + reg
        const float corr = bf2f(sC[lm * LDA + gn]);
        out[(row0 + lm) * DZV + gn] = acc[mt][nt][r] + corr;  // plain store: L2 merges lines
      }
    }
  }
}

extern "C" void kernel_launch(void* const* d_in, const int* in_sizes, int n_in,
                              void* d_out, int out_size, void* d_ws, size_t ws_size,
                              hipStream_t stream) {
  const float* z  = (const float*)d_in[0];
  const float* AW = (const float*)d_in[1];
  const float* h  = (const float*)d_in[2];
  float* out = (float*)d_out;
  unsigned short* AWp = (unsigned short*)d_ws;                     // 512 KB packed bf16
  float* Adiag = (float*)((char*)d_ws + DZV * DZV * sizeof(unsigned short)); // 2 KB

  pack_b<<<128, 256, 0, stream>>>(AW, AWp, Adiag);
  plrnn_step<<<65536 / BM, 512, 0, stream>>>(z, h, AWp, Adiag, out);
}

// Round 3
// 265.784 us; speedup vs baseline: 1.2865x; 1.0499x over previous
//
#include <hip/hip_runtime.h>
#include <hip/hip_bf16.h>

// PLRNN step: out = A*z + relu(z - rowmean(z)) @ W^T + h,  A=diag(AW), W=AW-diag
// Rewritten: out = (z_act @ AW^T) + [A*min(z,mu) + h]   (exact identity)
// Round 3: manual double-buffered register pipeline in the K-loop (prefetch
// s+1 frags before MFMAs of s), pre-barrier B prefetch, nt-inner store order.

#define DZV 512
#define BM 32
#define LDA 520   // LDS row stride (shorts): 1040 B, 16B-aligned, non-pow2 bank stride

typedef __attribute__((ext_vector_type(8))) short short8;  // 8 bf16 = 4 VGPRs
typedef __attribute__((ext_vector_type(4))) float f32x4;   // MFMA C/D frag

__device__ __forceinline__ unsigned short f2bf(float x) {
  __hip_bfloat16 b = __float2bfloat16(x);
  return __builtin_bit_cast(unsigned short, b);
}
__device__ __forceinline__ float bf2f(unsigned short u) {
  return __builtin_bit_cast(float, (unsigned int)u << 16);
}

// Prep: pack AW (fp32) into bf16 MFMA-B-fragment order + extract diagonal.
// Frag idx=(T*16+s)*64+L holds 8 bf16 = AW[T*16+(L&15)][s*32+(L>>4)*8 + j]:
// a wave's B-frag load (lane L reads idx base+L) is 1KB contiguous, L2-hot.
__global__ void pack_b(const float* __restrict__ AW, unsigned short* __restrict__ AWp,
                       float* __restrict__ Adiag) {
  int idx = blockIdx.x * 256 + threadIdx.x;     // 0..32767
  int L = idx & 63, s = (idx >> 6) & 15, T = idx >> 10;
  int n = T * 16 + (L & 15);
  int k = s * 32 + (L >> 4) * 8;
  const float4* src = (const float4*)(AW + n * DZV + k);
  float4 a = src[0], b = src[1];
  union { unsigned short u[8]; short8 v; } p;
  p.u[0] = f2bf(a.x); p.u[1] = f2bf(a.y); p.u[2] = f2bf(a.z); p.u[3] = f2bf(a.w);
  p.u[4] = f2bf(b.x); p.u[5] = f2bf(b.y); p.u[6] = f2bf(b.z); p.u[7] = f2bf(b.w);
  *(short8*)(AWp + idx * 8) = p.v;
  if (idx < DZV) Adiag[idx] = AW[idx * (DZV + 1)];
}

__global__ __launch_bounds__(512, 4) void plrnn_step(
    const float* __restrict__ z, const float* __restrict__ h,
    const unsigned short* __restrict__ AWp, const float* __restrict__ Adiag,
    float* __restrict__ out)
{
  __shared__ unsigned short sA[BM * LDA];  // z_act panel (bf16), 33.3 KB
  __shared__ unsigned short sC[BM * LDA];  // corr = A*min(z,mu)+h (bf16), 33.3 KB

  const int t = threadIdx.x;
  const int row0 = blockIdx.x * BM;

  const int lane = t & 63;
  const int wave = t >> 6;           // 8 waves cover N=512
  const int lr   = lane & 15;
  const int quad = lane >> 4;
  const int nbase = wave * 64;

  // B frag base pointers (packed global, lane-contiguous 1KB per frag-load)
  const unsigned short* bb[4];
  #pragma unroll
  for (int nt = 0; nt < 4; ++nt)
    bb[nt] = AWp + (((wave * 4 + nt) * 16) * 64 + lane) * 8;

  // ---- Phase 1: single coalesced pass over z; mean, relu->sA, corr->sC ----
  {
    const int r = t >> 4;          // 0..31, 16 threads per row (consecutive lanes)
    const int c = t & 15;
    const float4* zr = (const float4*)(z + (row0 + r) * DZV);
    float4 v[8];
    float s = 0.f;
    #pragma unroll
    for (int i = 0; i < 8; ++i) {
      v[i] = zr[c + i * 16];                   // coalesced 256B runs
      s += (v[i].x + v[i].y) + (v[i].z + v[i].w);
    }
    s += __shfl_xor(s, 1);
    s += __shfl_xor(s, 2);
    s += __shfl_xor(s, 4);
    s += __shfl_xor(s, 8);
    const float mu = s * (1.0f / 512.0f);
    #pragma unroll
    for (int i = 0; i < 8; ++i) {
      const int c4 = c + i * 16;               // float4 column index
      float4 Ad = ((const float4*)Adiag)[c4];  // L1-hot, 2KB shared
      float4 hv = ((const float4*)h)[c4];
      union { unsigned short u[4]; } pa, pc;
      pa.u[0] = f2bf(fmaxf(v[i].x - mu, 0.f));
      pa.u[1] = f2bf(fmaxf(v[i].y - mu, 0.f));
      pa.u[2] = f2bf(fmaxf(v[i].z - mu, 0.f));
      pa.u[3] = f2bf(fmaxf(v[i].w - mu, 0.f));
      pc.u[0] = f2bf(Ad.x * fminf(v[i].x, mu) + hv.x);
      pc.u[1] = f2bf(Ad.y * fminf(v[i].y, mu) + hv.y);
      pc.u[2] = f2bf(Ad.z * fminf(v[i].z, mu) + hv.z);
      pc.u[3] = f2bf(Ad.w * fminf(v[i].w, mu) + hv.w);
      *(ushort4*)&sA[r * LDA + c4 * 4] = *(ushort4*)pa.u;
      *(ushort4*)&sC[r * LDA + c4 * 4] = *(ushort4*)pc.u;
    }
  }

  // Pre-barrier B prefetch for s=0: loads fly during the barrier drain.
  short8 bf[2][4];
  #pragma unroll
  for (int nt = 0; nt < 4; ++nt)
    bf[0][nt] = *(const short8*)(bb[nt] + 0 * 512);

  __syncthreads();   // only barrier; K-loop below is barrier-free

  // ---- Phase 2: GEMM, 2M x 4N per wave, double-buffered register pipeline ----
  const unsigned short* a0 = &sA[(lr) * LDA + quad * 8];
  const unsigned short* a1 = &sA[(16 + lr) * LDA + quad * 8];

  short8 af[2][2];
  af[0][0] = *(const short8*)(a0);
  af[0][1] = *(const short8*)(a1);

  f32x4 acc[2][4];
  #pragma unroll
  for (int mt = 0; mt < 2; ++mt)
    #pragma unroll
    for (int nt = 0; nt < 4; ++nt)
      acc[mt][nt] = (f32x4){0.f, 0.f, 0.f, 0.f};

  #pragma unroll
  for (int s = 0; s < 16; ++s) {     // k = s*32
    const int cur = s & 1, nxt = cur ^ 1;
    if (s < 15) {                    // prefetch s+1 BEFORE computing s
      #pragma unroll
      for (int nt = 0; nt < 4; ++nt)
        bf[nxt][nt] = *(const short8*)(bb[nt] + (s + 1) * 512);  // L2, dwordx4
      af[nxt][0] = *(const short8*)(a0 + (s + 1) * 32);          // ds_read_b128
      af[nxt][1] = *(const short8*)(a1 + (s + 1) * 32);
    }
    #pragma unroll
    for (int nt = 0; nt < 4; ++nt) {
      acc[0][nt] = __builtin_amdgcn_mfma_f32_16x16x32_bf16(af[cur][0], bf[cur][nt], acc[0][nt], 0, 0, 0);
      acc[1][nt] = __builtin_amdgcn_mfma_f32_16x16x32_bf16(af[cur][1], bf[cur][nt], acc[1][nt], 0, 0, 0);
    }
  }

  // ---- Epilogue: out = acc + corr; nt innermost -> 4 adjacent 64B segments
  // per row issued back-to-back so L2 merges full lines.
  #pragma unroll
  for (int mt = 0; mt < 2; ++mt) {
    #pragma unroll
    for (int r = 0; r < 4; ++r) {
      const int lm = mt * 16 + quad * 4 + r;   // C/D layout: row = quad*4 + reg
      float corr[4];
      #pragma unroll
      for (int nt = 0; nt < 4; ++nt)
        corr[nt] = bf2f(sC[lm * LDA + nbase + nt * 16 + lr]);
      float* orow = out + (row0 + lm) * DZV + nbase + lr;
      #pragma unroll
      for (int nt = 0; nt < 4; ++nt)
        orow[nt * 16] = acc[mt][nt][r] + corr[nt];
    }
  }
}

extern "C" void kernel_launch(void* const* d_in, const int* in_sizes, int n_in,
                              void* d_out, int out_size, void* d_ws, size_t ws_size,
                              hipStream_t stream) {
  const float* z  = (const float*)d_in[0];
  const float* AW = (const float*)d_in[1];
  const float* h  = (const float*)d_in[2];
  float* out = (float*)d_out;
  unsigned short* AWp = (unsigned short*)d_ws;                     // 512 KB packed bf16
  float* Adiag = (float*)((char*)d_ws + DZV * DZV * sizeof(unsigned short)); // 2 KB

  pack_b<<<128, 256, 0, stream>>>(AW, AWp, Adiag);
  plrnn_step<<<65536 / BM, 512, 0, stream>>>(z, h, AWp, Adiag, out);
}